// Round 1
// baseline (526.436 us; speedup 1.0000x reference)
//
#include <hip/hip_runtime.h>

#define HW (512 * 512)
#define NBINS 256
#define NB 128
#define CHUNKS 32          // 16 rows per chunk
#define CPX4 2048          // float4s (= 8192 pixels) per chunk

// ---------------- workspace layout (bytes) ----------------
// 0      : counts[256]   int   (per-bin totals, batch-independent)
// 1024   : S1[128][256]  float
// 132096 : S2[128][256]  float
// total  : 263168

// ---- tiny kernel: per-bin pixel counts (depends only on bins) ----
__global__ __launch_bounds__(256) void countk(const int* __restrict__ bins,
                                              int* __restrict__ counts) {
    __shared__ int hist[NBINS];
    const int t = threadIdx.x;
    hist[t] = 0;
    __syncthreads();
    const int4* __restrict__ B4 = (const int4*)bins + blockIdx.x * CPX4;
    #pragma unroll
    for (int g = 0; g < 8; ++g) {
        int4 bb = B4[g * 256 + t];
        if (bb.x > 3 && bb.x < NBINS) atomicAdd(&hist[bb.x], 1);
        if (bb.y > 3 && bb.y < NBINS) atomicAdd(&hist[bb.y], 1);
        if (bb.z > 3 && bb.z < NBINS) atomicAdd(&hist[bb.z], 1);
        if (bb.w > 3 && bb.w < NBINS) atomicAdd(&hist[bb.w], 1);
    }
    __syncthreads();
    if (hist[t]) atomicAdd(&counts[t], hist[t]);
}

// ---- main pass: pure streaming, per-pixel LDS histogram atomics ----
// No staging, no perm, no per-pixel barrier structure. LDS = 2 KB ->
// ~8 blocks/CU resident; global loads perfectly coalesced float4.
__global__ __launch_bounds__(256) void pass(const float* __restrict__ parts,
                                            const float* __restrict__ projs,
                                            const int* __restrict__ bins,
                                            float* __restrict__ S1,
                                            float* __restrict__ S2) {
    __shared__ float h1[NBINS], h2[NBINS];
    const int t = threadIdx.x;
    const int chunk = blockIdx.x;
    const int b = blockIdx.y;
    h1[t] = 0.f;
    h2[t] = 0.f;
    __syncthreads();

    const float4* __restrict__ P4 = (const float4*)(parts + (size_t)b * HW) + chunk * CPX4;
    const float4* __restrict__ Q4 = (const float4*)(projs + (size_t)b * HW) + chunk * CPX4;
    const int4*   __restrict__ B4 = (const int4*)bins + chunk * CPX4;

    #pragma unroll 2
    for (int g = 0; g < 8; ++g) {
        const int idx = g * 256 + t;
        const float4 p = P4[idx];
        const float4 q = Q4[idx];
        const int4  bb = B4[idx];
        float n;
        n = p.x - q.x;
        if (bb.x > 3 && bb.x < NBINS) { atomicAdd(&h1[bb.x], fabsf(n)); atomicAdd(&h2[bb.x], n * n); }
        n = p.y - q.y;
        if (bb.y > 3 && bb.y < NBINS) { atomicAdd(&h1[bb.y], fabsf(n)); atomicAdd(&h2[bb.y], n * n); }
        n = p.z - q.z;
        if (bb.z > 3 && bb.z < NBINS) { atomicAdd(&h1[bb.z], fabsf(n)); atomicAdd(&h2[bb.z], n * n); }
        n = p.w - q.w;
        if (bb.w > 3 && bb.w < NBINS) { atomicAdd(&h1[bb.w], fabsf(n)); atomicAdd(&h2[bb.w], n * n); }
    }
    __syncthreads();

    const float v1 = h1[t];
    const float v2 = h2[t];
    if (v1 != 0.f) unsafeAtomicAdd(&S1[b * NBINS + t], v1);
    if (v2 != 0.f) unsafeAtomicAdd(&S2[b * NBINS + t], v2);
}

// ---- finalize: per-batch closed-form sum over bins ----
__global__ __launch_bounds__(256) void finalize(const float* __restrict__ S1,
                                                const float* __restrict__ S2,
                                                const int* __restrict__ counts,
                                                float* __restrict__ out) {
    const int b = blockIdx.x;
    const int t = threadIdx.x;
    float contrib = 0.f;
    if (t > 3) {   // valid bins 4..255
        float c = (float)counts[t];
        float s1 = S1[b * NBINS + t];
        float s2 = S2[b * NBINS + t];
        float mean = s1 / fmaxf(c, 1.f);
        float ssq = fmaxf(s2 - mean * s1, 0.f);          // = sum (a - mean)^2
        float var = ssq / fmaxf(c - 1.f, 1.f);
        contrib = -0.5f * s2 / var - c * logf(6.283185307179586f * var);
    }
    #pragma unroll
    for (int off = 32; off > 0; off >>= 1) contrib += __shfl_down(contrib, off, 64);
    __shared__ float w[4];
    if ((t & 63) == 0) w[t >> 6] = contrib;
    __syncthreads();
    if (t == 0) out[b] = w[0] + w[1] + w[2] + w[3];
}

extern "C" void kernel_launch(void* const* d_in, const int* in_sizes, int n_in,
                              void* d_out, int out_size, void* d_ws, size_t ws_size,
                              hipStream_t stream) {
    const float* parts = (const float*)d_in[0];
    const float* projs = (const float*)d_in[1];
    const int* bins    = (const int*)d_in[2];
    float* out = (float*)d_out;

    char* ws = (char*)d_ws;
    int*   counts = (int*)(ws + 0);
    float* S1     = (float*)(ws + 1024);
    float* S2     = (float*)(ws + 132096);

    hipMemsetAsync(d_ws, 0, 263168, stream);
    countk  <<<CHUNKS, 256, 0, stream>>>(bins, counts);
    pass    <<<dim3(CHUNKS, NB), 256, 0, stream>>>(parts, projs, bins, S1, S2);
    finalize<<<NB, 256, 0, stream>>>(S1, S2, counts, out);
}

// Round 3
// 517.122 us; speedup vs baseline: 1.0180x; 1.0180x over previous
//
#include <hip/hip_runtime.h>

#define HW (512 * 512)
#define NBINS 256
#define NB 128
#define NCOPY 8
#define HSTR 257           // copy stride: 257 % 32 = 1 -> rotates banks per copy
#define CHUNKS 32          // 16 rows per chunk
#define CPX4 2048          // float4s (= 8192 pixels) per chunk

// ---------------- workspace layout (bytes) ----------------
// 0      : counts[256]   int   (per-bin totals, batch-independent)
// 1024   : S1[128][256]  float
// 132096 : S2[128][256]  float
// total  : 263168

// ---- per-bin pixel counts (bins only); 8-copy replicated histogram ----
__global__ __launch_bounds__(256) void countk(const int* __restrict__ bins,
                                              int* __restrict__ counts) {
    __shared__ int hist[NCOPY * HSTR];
    const int t = threadIdx.x;
    for (int i = t; i < NCOPY * HSTR; i += 256) hist[i] = 0;
    __syncthreads();
    const int base = ((t >> 3) & 7) * HSTR;
    const int4* __restrict__ B4 = (const int4*)bins + blockIdx.x * 1024;
    #pragma unroll
    for (int g = 0; g < 4; ++g) {
        const int4 bb = B4[g * 256 + t];
        const int arr[4] = {bb.x, bb.y, bb.z, bb.w};
        int cb = -1, cnt = 0;
        #pragma unroll
        for (int m = 0; m < 4; ++m) {
            const int vb = (arr[m] > 3 && arr[m] < NBINS) ? arr[m] : -1;
            if (vb != cb) {
                if (cb >= 0) atomicAdd(&hist[base + cb], cnt);
                cb = vb; cnt = 0;
            }
            cnt += (vb >= 0) ? 1 : 0;
        }
        if (cb >= 0) atomicAdd(&hist[base + cb], cnt);
    }
    __syncthreads();
    int s = 0;
    #pragma unroll
    for (int c = 0; c < NCOPY; ++c) s += hist[c * HSTR + t];
    if (s) atomicAdd(&counts[t], s);
}

// ---- main pass: streaming + 8-copy replicated LDS histogram + quad run-merge ----
// Same-address ds_add serialization (round-1 killer) mitigated by:
//   copy = (lane>>3)&7  -> axis-region 64-way collisions become 8-way/copy;
//   copy offset 257 floats -> generic stride-4-bin region lands ~2-way/bank (free);
//   in-quad run merge -> ~1.5-2.5x fewer atomics.
__global__ __launch_bounds__(256) void pass(const float* __restrict__ parts,
                                            const float* __restrict__ projs,
                                            const int* __restrict__ bins,
                                            float* __restrict__ S1,
                                            float* __restrict__ S2) {
    __shared__ float h1[NCOPY * HSTR], h2[NCOPY * HSTR];
    const int t = threadIdx.x;
    for (int i = t; i < NCOPY * HSTR; i += 256) { h1[i] = 0.f; h2[i] = 0.f; }
    __syncthreads();

    const int chunk = blockIdx.x;
    const int b = blockIdx.y;
    const int base = ((t >> 3) & 7) * HSTR;

    const float4* __restrict__ P4 = (const float4*)(parts + (size_t)b * HW) + chunk * CPX4;
    const float4* __restrict__ Q4 = (const float4*)(projs + (size_t)b * HW) + chunk * CPX4;
    const int4*   __restrict__ B4 = (const int4*)bins + chunk * CPX4;

    #pragma unroll 2
    for (int g = 0; g < 8; ++g) {
        const int idx = g * 256 + t;
        const float4 p = P4[idx];
        const float4 q = Q4[idx];
        const int4  bb = B4[idx];
        const int   barr[4] = {bb.x, bb.y, bb.z, bb.w};
        const float narr[4] = {p.x - q.x, p.y - q.y, p.z - q.z, p.w - q.w};
        int cb = -1; float a1 = 0.f, a2 = 0.f;
        #pragma unroll
        for (int m = 0; m < 4; ++m) {
            const int vb = (barr[m] > 3 && barr[m] < NBINS) ? barr[m] : -1;
            if (vb != cb) {
                if (cb >= 0) { atomicAdd(&h1[base + cb], a1); atomicAdd(&h2[base + cb], a2); }
                cb = vb; a1 = 0.f; a2 = 0.f;
            }
            if (vb >= 0) { const float n = narr[m]; a1 += fabsf(n); a2 += n * n; }
        }
        if (cb >= 0) { atomicAdd(&h1[base + cb], a1); atomicAdd(&h2[base + cb], a2); }
    }
    __syncthreads();

    float v1 = 0.f, v2 = 0.f;
    #pragma unroll
    for (int c = 0; c < NCOPY; ++c) { v1 += h1[c * HSTR + t]; v2 += h2[c * HSTR + t]; }
    if (v1 != 0.f) unsafeAtomicAdd(&S1[b * NBINS + t], v1);
    if (v2 != 0.f) unsafeAtomicAdd(&S2[b * NBINS + t], v2);
}

// ---- finalize: per-batch closed-form sum over bins ----
__global__ __launch_bounds__(256) void finalize(const float* __restrict__ S1,
                                                const float* __restrict__ S2,
                                                const int* __restrict__ counts,
                                                float* __restrict__ out) {
    const int b = blockIdx.x;
    const int t = threadIdx.x;
    float contrib = 0.f;
    if (t > 3) {   // valid bins 4..255
        float c = (float)counts[t];
        float s1 = S1[b * NBINS + t];
        float s2 = S2[b * NBINS + t];
        float mean = s1 / fmaxf(c, 1.f);
        float ssq = fmaxf(s2 - mean * s1, 0.f);          // = sum (a - mean)^2
        float var = ssq / fmaxf(c - 1.f, 1.f);
        contrib = -0.5f * s2 / var - c * logf(6.283185307179586f * var);
    }
    #pragma unroll
    for (int off = 32; off > 0; off >>= 1) contrib += __shfl_down(contrib, off, 64);
    __shared__ float w[4];
    if ((t & 63) == 0) w[t >> 6] = contrib;
    __syncthreads();
    if (t == 0) out[b] = w[0] + w[1] + w[2] + w[3];
}

extern "C" void kernel_launch(void* const* d_in, const int* in_sizes, int n_in,
                              void* d_out, int out_size, void* d_ws, size_t ws_size,
                              hipStream_t stream) {
    const float* parts = (const float*)d_in[0];
    const float* projs = (const float*)d_in[1];
    const int* bins    = (const int*)d_in[2];
    float* out = (float*)d_out;

    char* ws = (char*)d_ws;
    int*   counts = (int*)(ws + 0);
    float* S1     = (float*)(ws + 1024);
    float* S2     = (float*)(ws + 132096);

    hipMemsetAsync(d_ws, 0, 263168, stream);
    countk  <<<64, 256, 0, stream>>>(bins, counts);          // 4096 px / block
    pass    <<<dim3(CHUNKS, NB), 256, 0, stream>>>(parts, projs, bins, S1, S2);
    finalize<<<NB, 256, 0, stream>>>(S1, S2, counts, out);
}